// Round 2
// baseline (871.308 us; speedup 1.0000x reference)
//
#include <hip/hip_runtime.h>
#include <hip/hip_bf16.h>

#define N_NODES 100000
#define N_EDGES 3200000
#define CH 32
#define NK 9
#define YSTRIDE (NK * CH)  // 288

#define SBS 512
#define NBLK1 ((N_NODES + SBS - 1) / SBS)  // 196

typedef __hip_bfloat16 bf16;

// ---------------------------------------------------------------------------
// CSR build step 1: count in-degree
// ---------------------------------------------------------------------------
__global__ __launch_bounds__(256) void count_kernel(const int* __restrict__ ei,
                                                    int* __restrict__ cnt) {
    int e = blockIdx.x * 256 + threadIdx.x;
    if (e < N_EDGES) atomicAdd(&cnt[ei[N_EDGES + e]], 1);
}

// step 2a: per-block exclusive scan (deterministic)
__global__ __launch_bounds__(SBS) void scan1_kernel(const int* __restrict__ cnt,
                                                    int* __restrict__ start,
                                                    int* __restrict__ bsum) {
    __shared__ int s[SBS];
    int t = threadIdx.x;
    int g = blockIdx.x * SBS + t;
    int v = (g < N_NODES) ? cnt[g] : 0;
    s[t] = v;
    __syncthreads();
    for (int off = 1; off < SBS; off <<= 1) {
        int u = (t >= off) ? s[t - off] : 0;
        __syncthreads();
        s[t] += u;
        __syncthreads();
    }
    if (g < N_NODES) start[g] = s[t] - v;  // exclusive
    if (t == SBS - 1) bsum[blockIdx.x] = s[t];
}

// step 2b: scan the block sums (single block)
__global__ __launch_bounds__(256) void scan2_kernel(const int* __restrict__ bsum,
                                                    int* __restrict__ boff) {
    __shared__ int s[256];
    int t = threadIdx.x;
    int v = (t < NBLK1) ? bsum[t] : 0;
    s[t] = v;
    __syncthreads();
    for (int off = 1; off < 256; off <<= 1) {
        int u = (t >= off) ? s[t - off] : 0;
        __syncthreads();
        s[t] += u;
        __syncthreads();
    }
    if (t < NBLK1) boff[t] = s[t] - v;
}

// step 2c: add block offsets, init cursor
__global__ __launch_bounds__(SBS) void scan3_kernel(int* __restrict__ start,
                                                    const int* __restrict__ boff,
                                                    int* __restrict__ cursor) {
    int g = blockIdx.x * SBS + threadIdx.x;
    if (g < N_NODES) {
        int v = start[g] + boff[blockIdx.x];
        start[g] = v;
        cursor[g] = v;
    }
}

// step 3: place {row, pa, pb} records into destination-sorted slots
__global__ __launch_bounds__(256) void place_kernel(const float* __restrict__ pseudo,
                                                    const int* __restrict__ ei,
                                                    int* __restrict__ cursor,
                                                    int4* __restrict__ edata) {
    int e = blockIdx.x * 256 + threadIdx.x;
    if (e >= N_EDGES) return;
    int col = ei[N_EDGES + e];
    int row = ei[e];
    float2 pp = ((const float2*)pseudo)[e];
    int pos = atomicAdd(&cursor[col], 1);
    int4 d;
    d.x = row;
    d.y = __float_as_int(pp.x);
    d.z = __float_as_int(pp.y);
    d.w = 0;
    edata[pos] = d;
}

// ---------------------------------------------------------------------------
// y[n,k,o] = sum_i x[n,i] * w[k,i,o]  (bf16 output, 57.6 MB, LLC-resident)
// ---------------------------------------------------------------------------
__global__ __launch_bounds__(256) void yprep_kernel(const float* __restrict__ x,
                                                    const float* __restrict__ w,
                                                    bf16* __restrict__ y) {
    __shared__ float ws[NK * CH * CH];  // 36 KB
    int tid = threadIdx.x;
    for (int j = tid; j < NK * CH * CH; j += 256) ws[j] = w[j];
    __syncthreads();

    int idx = blockIdx.x * 256 + tid;
    if (idx >= N_NODES * YSTRIDE) return;
    int n = idx / YSTRIDE;
    int r = idx - n * YSTRIDE;
    int k = r >> 5;
    int o = r & 31;
    const float* xr = x + n * CH;
    const float* wk = ws + k * (CH * CH) + o;
    float s = 0.f;
#pragma unroll
    for (int i = 0; i < CH; ++i) s += xr[i] * wk[i * CH];  // ws conflict-free (bank = o)
    y[idx] = __float2bfloat16(s);
}

// ---------------------------------------------------------------------------
// Pull-style aggregation: one 64-lane wave per destination node.
// Lanes 0-31 / 32-63 each own an output channel and process alternating edges.
// Zero f32 atomics; root linear fused; out written exactly once.
// ---------------------------------------------------------------------------
__global__ __launch_bounds__(256) void gather_kernel(const float* __restrict__ x,
                                                     const int* __restrict__ start,
                                                     const int* __restrict__ cnt,
                                                     const int4* __restrict__ edata,
                                                     const bf16* __restrict__ y,
                                                     const float* __restrict__ rw,
                                                     const float* __restrict__ rb,
                                                     float* __restrict__ out) {
    __shared__ float rws[CH * CH];  // transposed: rws[i*CH+o] = rw[o*CH+i]
    __shared__ float rbs[CH];
    int tid = threadIdx.x;
    for (int j = tid; j < CH * CH; j += 256) {
        int o = j >> 5, i = j & 31;
        rws[i * CH + o] = rw[j];
    }
    if (tid < CH) rbs[tid] = rb[tid];
    __syncthreads();

    int wid = tid >> 6;
    int lane = tid & 63;
    int half = lane >> 5;  // which half-wave
    int o = lane & 31;     // output channel
    int n = blockIdx.x * 4 + wid;
    if (n >= N_NODES) return;

    int s0 = start[n];
    int dg = cnt[n];
    float acc = 0.f;
    for (int j = half; j < dg; j += 2) {
        int4 ed = edata[s0 + j];  // lane-uniform broadcast, sequential per node
        int row = ed.x;
        float pa = __int_as_float(ed.y);
        float pb = __int_as_float(ed.z);
        pa = fminf(fmaxf(pa, 0.f), 1.f);
        pb = fminf(fmaxf(pb, 0.f), 1.f);
        int ia = pa < 0.5f ? 0 : 1;
        int ib = pb < 0.5f ? 0 : 1;
        float wa1 = 2.f * (pa - 0.5f * (float)ia);
        float wa0 = 1.f - wa1;
        float wb1 = 2.f * (pb - 0.5f * (float)ib);
        float wb0 = 1.f - wb1;
        // 4 nonzero basis entries -> 4 coalesced 64B bf16 reads (LLC-resident)
        const bf16* yr = y + (size_t)row * YSTRIDE + (ia * 3 + ib) * CH + o;
        acc += wa0 * wb0 * __bfloat162float(yr[0])
             + wa0 * wb1 * __bfloat162float(yr[CH])
             + wa1 * wb0 * __bfloat162float(yr[3 * CH])
             + wa1 * wb1 * __bfloat162float(yr[4 * CH]);
    }
    acc += __shfl_down(acc, 32);  // combine the two half-waves
    if (half == 0) {
        float a = acc / fmaxf((float)dg, 1.f);
        const float* xr = x + n * CH;
        float s = rbs[o];
#pragma unroll
        for (int i = 0; i < CH; ++i) s += xr[i] * rws[i * CH + o];  // conflict-free
        out[n * CH + o] = a + s;
    }
}

// ---------------------------------------------------------------------------
extern "C" void kernel_launch(void* const* d_in, const int* in_sizes, int n_in,
                              void* d_out, int out_size, void* d_ws, size_t ws_size,
                              hipStream_t stream) {
    const float* x      = (const float*)d_in[0];
    const float* pseudo = (const float*)d_in[1];
    const float* weight = (const float*)d_in[2];
    const float* root_w = (const float*)d_in[3];
    const float* root_b = (const float*)d_in[4];
    const int*   ei     = (const int*)d_in[5];
    float* out = (float*)d_out;

    // ws layout (all 16B-aligned): total ~110.0 MB (< 116.2 MB proven available)
    int* cnt    = (int*)d_ws;          // 102400 ints (padded)
    int* start  = cnt + 102400;
    int* cursor = start + 102400;
    int* bsum   = cursor + 102400;     // 256
    int* boff   = bsum + 256;          // 256
    int4* edata = (int4*)(boff + 256); // N_EDGES * 16 B = 51.2 MB
    bf16* y     = (bf16*)(edata + N_EDGES);  // 57.6 MB

    hipMemsetAsync(cnt, 0, N_NODES * sizeof(int), stream);
    count_kernel<<<(N_EDGES + 255) / 256, 256, 0, stream>>>(ei, cnt);
    scan1_kernel<<<NBLK1, SBS, 0, stream>>>(cnt, start, bsum);
    scan2_kernel<<<1, 256, 0, stream>>>(bsum, boff);
    scan3_kernel<<<NBLK1, SBS, 0, stream>>>(start, boff, cursor);
    place_kernel<<<(N_EDGES + 255) / 256, 256, 0, stream>>>(pseudo, ei, cursor, edata);
    yprep_kernel<<<(N_NODES * YSTRIDE + 255) / 256, 256, 0, stream>>>(x, weight, y);
    gather_kernel<<<(N_NODES + 3) / 4, 256, 0, stream>>>(x, start, cnt, edata, y,
                                                          root_w, root_b, out);
}

// Round 3
// 625.122 us; speedup vs baseline: 1.3938x; 1.3938x over previous
//
#include <hip/hip_runtime.h>
#include <hip/hip_bf16.h>

#define N_NODES 100000
#define N_EDGES 3200000
#define CH 32
#define NK 9
#define YSTRIDE (NK * CH)  // 288

#define SBS 512
#define NBLK1 ((N_NODES + SBS - 1) / SBS)  // 196
#define TN 32               // nodes per yprep block

typedef __hip_bfloat16 bf16;

// ---------------------------------------------------------------------------
// CSR build step 1: count in-degree
// ---------------------------------------------------------------------------
__global__ __launch_bounds__(256) void count_kernel(const int* __restrict__ ei,
                                                    int* __restrict__ cnt) {
    int e = blockIdx.x * 256 + threadIdx.x;
    if (e < N_EDGES) atomicAdd(&cnt[ei[N_EDGES + e]], 1);
}

// step 2a: per-block exclusive scan (deterministic)
__global__ __launch_bounds__(SBS) void scan1_kernel(const int* __restrict__ cnt,
                                                    int* __restrict__ start,
                                                    int* __restrict__ bsum) {
    __shared__ int s[SBS];
    int t = threadIdx.x;
    int g = blockIdx.x * SBS + t;
    int v = (g < N_NODES) ? cnt[g] : 0;
    s[t] = v;
    __syncthreads();
    for (int off = 1; off < SBS; off <<= 1) {
        int u = (t >= off) ? s[t - off] : 0;
        __syncthreads();
        s[t] += u;
        __syncthreads();
    }
    if (g < N_NODES) start[g] = s[t] - v;  // exclusive
    if (t == SBS - 1) bsum[blockIdx.x] = s[t];
}

// step 2b: scan the block sums (single block)
__global__ __launch_bounds__(256) void scan2_kernel(const int* __restrict__ bsum,
                                                    int* __restrict__ boff) {
    __shared__ int s[256];
    int t = threadIdx.x;
    int v = (t < NBLK1) ? bsum[t] : 0;
    s[t] = v;
    __syncthreads();
    for (int off = 1; off < 256; off <<= 1) {
        int u = (t >= off) ? s[t - off] : 0;
        __syncthreads();
        s[t] += u;
        __syncthreads();
    }
    if (t < NBLK1) boff[t] = s[t] - v;
}

// step 2c: add block offsets, init cursor
__global__ __launch_bounds__(SBS) void scan3_kernel(int* __restrict__ start,
                                                    const int* __restrict__ boff,
                                                    int* __restrict__ cursor) {
    int g = blockIdx.x * SBS + threadIdx.x;
    if (g < N_NODES) {
        int v = start[g] + boff[blockIdx.x];
        start[g] = v;
        cursor[g] = v;
    }
}

// step 3: place 8-byte records {row|ia|ib, wa1_u16|wb1_u16} into dest-sorted slots
__global__ __launch_bounds__(256) void place_kernel(const float* __restrict__ pseudo,
                                                    const int* __restrict__ ei,
                                                    int* __restrict__ cursor,
                                                    uint2* __restrict__ edata) {
    int e = blockIdx.x * 256 + threadIdx.x;
    if (e >= N_EDGES) return;
    int col = ei[N_EDGES + e];
    int row = ei[e];
    float2 pp = ((const float2*)pseudo)[e];
    float pa = fminf(fmaxf(pp.x, 0.f), 1.f);
    float pb = fminf(fmaxf(pp.y, 0.f), 1.f);
    int ia = pa < 0.5f ? 0 : 1;
    int ib = pb < 0.5f ? 0 : 1;
    float wa1 = 2.f * (pa - 0.5f * (float)ia);   // in [0,1]
    float wb1 = 2.f * (pb - 0.5f * (float)ib);
    unsigned qa = (unsigned)(wa1 * 65535.f + 0.5f);
    unsigned qb = (unsigned)(wb1 * 65535.f + 0.5f);
    int pos = atomicAdd(&cursor[col], 1);
    uint2 d;
    d.x = (unsigned)row | ((unsigned)ia << 17) | ((unsigned)ib << 18);
    d.y = qa | (qb << 16);
    edata[pos] = d;
}

// ---------------------------------------------------------------------------
// y[n,k,o] = sum_i x[n,i] * w[k,i,o]  (bf16, 57.6 MB)
// 32 nodes/block; thread = (node g, o-quad o4); 9 float4 accumulators.
// LDS reads are 8-distinct-address broadcasts -> conflict-free.
// ---------------------------------------------------------------------------
__global__ __launch_bounds__(256) void yprep_kernel(const float* __restrict__ x,
                                                    const float* __restrict__ w,
                                                    bf16* __restrict__ y) {
    __shared__ float ws[NK * CH * CH];  // 36 KB, [k][i][o]
    __shared__ float xs[TN * 36];       // padded rows (36 floats) for bank spread
    int tid = threadIdx.x;

    const float4* w4 = (const float4*)w;
    float4* ws4 = (float4*)ws;
    for (int j = tid; j < NK * CH * CH / 4; j += 256) ws4[j] = w4[j];

    int n0 = blockIdx.x * TN;
    {
        int n = tid >> 3, i4 = tid & 7;  // 256 threads = 32 nodes x 8 quads
        float4 v = ((const float4*)(x + (size_t)(n0 + n) * CH))[i4];
        *(float4*)(xs + n * 36 + i4 * 4) = v;  // 16B-aligned (36*4=144B)
    }
    __syncthreads();

    int o4 = tid & 7;
    int g = tid >> 3;
    float4 acc[NK];
#pragma unroll
    for (int k = 0; k < NK; ++k) acc[k] = make_float4(0.f, 0.f, 0.f, 0.f);

    const float4* wsv = (const float4*)ws;  // index: k*256 + i*8 + o4
#pragma unroll 4
    for (int i = 0; i < CH; ++i) {
        float xv = xs[g * 36 + i];
#pragma unroll
        for (int k = 0; k < NK; ++k) {
            float4 wv = wsv[k * 256 + i * 8 + o4];
            acc[k].x += xv * wv.x;
            acc[k].y += xv * wv.y;
            acc[k].z += xv * wv.z;
            acc[k].w += xv * wv.w;
        }
    }

    bf16* yb = y + (size_t)(n0 + g) * YSTRIDE + o4 * 4;
#pragma unroll
    for (int k = 0; k < NK; ++k) {
        union { bf16 h[4]; uint2 u; } pk;
        pk.h[0] = __float2bfloat16(acc[k].x);
        pk.h[1] = __float2bfloat16(acc[k].y);
        pk.h[2] = __float2bfloat16(acc[k].z);
        pk.h[3] = __float2bfloat16(acc[k].w);
        *(uint2*)(yb + k * CH) = pk.u;  // 8B-aligned
    }
}

// ---------------------------------------------------------------------------
// Pull aggregation: one 64-lane wave per node; halves process alternate edges.
// ---------------------------------------------------------------------------
__global__ __launch_bounds__(256) void gather_kernel(const float* __restrict__ x,
                                                     const int* __restrict__ start,
                                                     const int* __restrict__ cnt,
                                                     const uint2* __restrict__ edata,
                                                     const bf16* __restrict__ y,
                                                     const float* __restrict__ rw,
                                                     const float* __restrict__ rb,
                                                     float* __restrict__ out) {
    __shared__ float rws[CH * CH];  // transposed: rws[i*CH+o] = rw[o*CH+i]
    __shared__ float rbs[CH];
    int tid = threadIdx.x;
    for (int j = tid; j < CH * CH; j += 256) {
        int o = j >> 5, i = j & 31;
        rws[i * CH + o] = rw[j];
    }
    if (tid < CH) rbs[tid] = rb[tid];
    __syncthreads();

    int wid = tid >> 6;
    int lane = tid & 63;
    int half = lane >> 5;
    int o = lane & 31;
    int n = blockIdx.x * 4 + wid;
    if (n >= N_NODES) return;

    int s0 = start[n];
    int dg = cnt[n];
    float acc = 0.f;
    for (int j = half; j < dg; j += 2) {
        uint2 ed = edata[s0 + j];  // 8B, lane-uniform broadcast
        int row = ed.x & 0x1FFFF;
        int ia = (ed.x >> 17) & 1;
        int ib = (ed.x >> 18) & 1;
        float wa1 = (float)(ed.y & 0xFFFF) * (1.f / 65535.f);
        float wb1 = (float)(ed.y >> 16) * (1.f / 65535.f);
        float wa0 = 1.f - wa1;
        float wb0 = 1.f - wb1;
        const bf16* yr = y + (size_t)row * YSTRIDE + (ia * 3 + ib) * CH + o;
        acc += (wa0 * wb0) * __bfloat162float(yr[0])
             + (wa0 * wb1) * __bfloat162float(yr[CH])
             + (wa1 * wb0) * __bfloat162float(yr[3 * CH])
             + (wa1 * wb1) * __bfloat162float(yr[4 * CH]);
    }
    acc += __shfl_down(acc, 32);
    if (half == 0) {
        float a = acc / fmaxf((float)dg, 1.f);
        const float* xr = x + n * CH;
        float s = rbs[o];
#pragma unroll
        for (int i = 0; i < CH; ++i) s += xr[i] * rws[i * CH + o];
        out[n * CH + o] = a + s;
    }
}

// ---------------------------------------------------------------------------
extern "C" void kernel_launch(void* const* d_in, const int* in_sizes, int n_in,
                              void* d_out, int out_size, void* d_ws, size_t ws_size,
                              hipStream_t stream) {
    const float* x      = (const float*)d_in[0];
    const float* pseudo = (const float*)d_in[1];
    const float* weight = (const float*)d_in[2];
    const float* root_w = (const float*)d_in[3];
    const float* root_b = (const float*)d_in[4];
    const int*   ei     = (const int*)d_in[5];
    float* out = (float*)d_out;

    // ws layout: ~85 MB total
    int* cnt    = (int*)d_ws;            // 102400
    int* start  = cnt + 102400;
    int* cursor = start + 102400;
    int* bsum   = cursor + 102400;       // 256
    int* boff   = bsum + 256;            // 256
    uint2* edata = (uint2*)(boff + 256); // 25.6 MB
    bf16* y     = (bf16*)(edata + N_EDGES);  // 57.6 MB

    hipMemsetAsync(cnt, 0, N_NODES * sizeof(int), stream);
    count_kernel<<<(N_EDGES + 255) / 256, 256, 0, stream>>>(ei, cnt);
    scan1_kernel<<<NBLK1, SBS, 0, stream>>>(cnt, start, bsum);
    scan2_kernel<<<1, 256, 0, stream>>>(bsum, boff);
    scan3_kernel<<<NBLK1, SBS, 0, stream>>>(start, boff, cursor);
    place_kernel<<<(N_EDGES + 255) / 256, 256, 0, stream>>>(pseudo, ei, cursor, edata);
    yprep_kernel<<<(N_NODES + TN - 1) / TN, 256, 0, stream>>>(x, weight, y);
    gather_kernel<<<(N_NODES + 3) / 4, 256, 0, stream>>>(x, start, cnt, edata, y,
                                                          root_w, root_b, out);
}